// Round 9
// baseline (1734.854 us; speedup 1.0000x reference)
//
#include <hip/hip_runtime.h>

#define NCH   256
#define M_PIX 262144
#define MPAD  266240   // 520*512 ; >= M_PIX + 8*512 worst-case alignment pad
#define LDA   40       // padded LDS leading dim (bf16 elements) for 32-wide k tiles

typedef short bf16x8 __attribute__((ext_vector_type(8)));
typedef float f32x4  __attribute__((ext_vector_type(4)));

__device__ __forceinline__ unsigned short f2bf(float f) {
  union { float f; unsigned u; } v; v.f = f;
  unsigned r = v.u + 0x7FFFu + ((v.u >> 16) & 1u);
  return (unsigned short)(r >> 16);
}
__device__ __forceinline__ float bf2f(unsigned short h) {
  union { unsigned u; float f; } v; v.u = ((unsigned)h) << 16;
  return v.f;
}

// ---------------- histogram: per-2048-pixel-block label counts, both segs ----
__global__ __launch_bounds__(256) void k_hist(const int* __restrict__ seg_c,
                                              const int* __restrict__ seg_s,
                                              int* __restrict__ hist) {
  __shared__ int h[16];
  int t = threadIdx.x;
  if (t < 16) h[t] = 0;
  __syncthreads();
  int p0 = blockIdx.x * 2048 + t * 8;
#pragma unroll
  for (int e = 0; e < 8; ++e) {
    atomicAdd(&h[seg_c[p0 + e] & 7], 1);
    atomicAdd(&h[8 + (seg_s[p0 + e] & 7)], 1);
  }
  __syncthreads();
  if (t < 8) hist[blockIdx.x * 8 + t] = h[t];
  else if (t < 16) hist[1024 + blockIdx.x * 8 + (t - 8)] = h[t];
}

// ---------------- scan: totals, 512-aligned offsets, per-block bases, valid --
__global__ __launch_bounds__(256) void k_scan(const int* __restrict__ hist,
                                              int* __restrict__ base,
                                              int* __restrict__ off,
                                              int* __restrict__ cnt,
                                              int* __restrict__ valid) {
  __shared__ int lh[2048];
  __shared__ int tot[16];
  __shared__ int loff[2][9];
  int t = threadIdx.x;
  for (int i = t; i < 2048; i += 256) lh[i] = hist[i];
  __syncthreads();
  if (t < 16) {
    int s = t >> 3, l = t & 7, acc = 0;
    for (int b = 0; b < 128; ++b) acc += lh[s * 1024 + b * 8 + l];
    tot[t] = acc;
  }
  __syncthreads();
  if (t < 2) {
    int run = 0;
    for (int l = 0; l < 8; ++l) {
      loff[t][l] = run;
      run = (run + tot[t * 8 + l] + 511) & ~511;
    }
    loff[t][8] = run;
    for (int l = 0; l < 9; ++l) off[t * 9 + l] = loff[t][l];
    for (int l = 0; l < 8; ++l) cnt[t * 8 + l] = tot[t * 8 + l];
  }
  __syncthreads();
  if (t < 8) {
    long nc = tot[t], ns = tot[8 + t];
    valid[t] = (nc > 10 && ns > 10 && nc < 100 * ns && ns < 100 * nc) ? 1 : 0;
  }
  if (t < 16) {
    int s = t >> 3, l = t & 7;
    int run = loff[s][l];
    for (int b = 0; b < 128; ++b) {
      base[s * 1024 + b * 8 + l] = run;
      run += lh[s * 1024 + b * 8 + l];
    }
  }
}

// ---------------- rank: stable per-pixel destination slot (counting sort) ----
__global__ __launch_bounds__(256) void k_rank(const int* __restrict__ seg_c,
                                              const int* __restrict__ seg_s,
                                              const int* __restrict__ base,
                                              int* __restrict__ dst) {
  __shared__ int sc[8 * 272];
  __shared__ int rb[256 * 8];
  __shared__ int bb[8];
  int t = threadIdx.x;
  for (int s = 0; s < 2; ++s) {
    const int* seg = s ? seg_s : seg_c;
    const int* bas = base + s * 1024 + blockIdx.x * 8;
    int* dd = dst + (size_t)s * M_PIX;
    int p0 = blockIdx.x * 2048 + t * 8;
    unsigned pk2 = 0, cpk = 0;
#pragma unroll
    for (int e = 0; e < 8; ++e) {
      int lb = seg[p0 + e] & 7;
      pk2 |= (unsigned)lb << (3 * e);
      cpk += 1u << (4 * lb);
    }
#pragma unroll
    for (int lq = 0; lq < 8; ++lq) sc[lq * 272 + t] = (int)((cpk >> (4 * lq)) & 15u);
    if (t < 8) bb[t] = bas[t];
    __syncthreads();
    for (int d = 1; d < 256; d <<= 1) {
      int v[8];
#pragma unroll
      for (int lq = 0; lq < 8; ++lq)
        v[lq] = sc[lq * 272 + t] + ((t >= d) ? sc[lq * 272 + t - d] : 0);
      __syncthreads();
#pragma unroll
      for (int lq = 0; lq < 8; ++lq) sc[lq * 272 + t] = v[lq];
      __syncthreads();
    }
#pragma unroll
    for (int lq = 0; lq < 8; ++lq)
      rb[t * 8 + lq] = bb[lq] + sc[lq * 272 + t] - (int)((cpk >> (4 * lq)) & 15u);
#pragma unroll
    for (int e = 0; e < 8; ++e) {
      int lb = (int)((pk2 >> (3 * e)) & 7u);
      int dpos = rb[t * 8 + lb]++;
      dd[p0 + e] = dpos;
    }
    __syncthreads();
  }
}

// ---------------- zero the alignment pads of P -------------------------------
__global__ __launch_bounds__(256) void k_padzero(unsigned short* __restrict__ P,
                                                 const int* __restrict__ off,
                                                 const int* __restrict__ cnt) {
  int l = blockIdx.x;
  int c0, c1;
  if (l < 8) { c0 = off[l] + cnt[l]; c1 = off[l + 1]; }
  else       { c0 = off[8];          c1 = MPAD; }
  int w = c1 - c0;
  if (w <= 0) return;
  for (int r = 0; r < 256; ++r)
    for (int cc = threadIdx.x; cc < w; cc += 256)
      P[(size_t)r * MPAD + c0 + cc] = 0;
}

// ---------------- pack: coalesced-both-sides via LDS local sort --------------
__global__ __launch_bounds__(256) void k_pack(const float* __restrict__ feat,
                                              const int* __restrict__ seg,
                                              const int* __restrict__ dst,
                                              const int* __restrict__ base,
                                              unsigned short* __restrict__ P) {
  int b = blockIdx.x, g = blockIdx.y, t = threadIdx.x;
  int p0 = b * 2048;
  __shared__ unsigned short buf[8][2048];
  __shared__ int h[8], lbase[9], gbase[8];
  if (t < 8) { h[t] = 0; gbase[t] = base[b * 8 + t]; }
  __syncthreads();
  int lb[8], slot[8], gd[8];
#pragma unroll
  for (int i = 0; i < 8; ++i) {
    lb[i] = seg[p0 + i * 256 + t] & 7;
    atomicAdd(&h[lb[i]], 1);
  }
  __syncthreads();
  if (t == 0) {
    int run = 0;
    for (int l = 0; l < 8; ++l) { lbase[l] = run; run += h[l]; }
    lbase[8] = run;
  }
  __syncthreads();
#pragma unroll
  for (int i = 0; i < 8; ++i)
    slot[i] = lbase[lb[i]] + (dst[p0 + i * 256 + t] - gbase[lb[i]]);
#pragma unroll
  for (int i = 0; i < 8; ++i) {
    int q = i * 256 + t;
    int l = 0;
    while (l < 7 && q >= lbase[l + 1]) ++l;
    gd[i] = gbase[l] + q - lbase[l];
  }
  int n0 = g * 32;
#pragma unroll 1
  for (int cp = 0; cp < 4; ++cp) {
#pragma unroll
    for (int c = 0; c < 8; ++c) {
      const float* fp = &feat[(size_t)(n0 + cp * 8 + c) * M_PIX + p0];
#pragma unroll
      for (int i = 0; i < 8; ++i)
        buf[c][slot[i]] = f2bf(fp[i * 256 + t]);
    }
    __syncthreads();
#pragma unroll
    for (int c = 0; c < 8; ++c) {
      unsigned short* pp = &P[(size_t)(n0 + cp * 8 + c) * MPAD];
#pragma unroll
      for (int i = 0; i < 8; ++i)
        pp[gd[i]] = buf[c][i * 256 + t];
    }
    __syncthreads();
  }
}

// ---------------- unpack: mirrored (contiguous reads, coalesced f32 writes) --
__global__ __launch_bounds__(256) void k_unpack(const unsigned short* __restrict__ P,
                                                const int* __restrict__ seg,
                                                const int* __restrict__ dst,
                                                const int* __restrict__ base,
                                                float* __restrict__ out) {
  int b = blockIdx.x, g = blockIdx.y, t = threadIdx.x;
  int p0 = b * 2048;
  __shared__ unsigned short buf[8][2048];
  __shared__ int h[8], lbase[9], gbase[8];
  if (t < 8) { h[t] = 0; gbase[t] = base[b * 8 + t]; }
  __syncthreads();
  int lb[8], slot[8], gd[8];
#pragma unroll
  for (int i = 0; i < 8; ++i) {
    lb[i] = seg[p0 + i * 256 + t] & 7;
    atomicAdd(&h[lb[i]], 1);
  }
  __syncthreads();
  if (t == 0) {
    int run = 0;
    for (int l = 0; l < 8; ++l) { lbase[l] = run; run += h[l]; }
    lbase[8] = run;
  }
  __syncthreads();
#pragma unroll
  for (int i = 0; i < 8; ++i)
    slot[i] = lbase[lb[i]] + (dst[p0 + i * 256 + t] - gbase[lb[i]]);
#pragma unroll
  for (int i = 0; i < 8; ++i) {
    int q = i * 256 + t;
    int l = 0;
    while (l < 7 && q >= lbase[l + 1]) ++l;
    gd[i] = gbase[l] + q - lbase[l];
  }
  int n0 = g * 32;
#pragma unroll 1
  for (int cp = 0; cp < 4; ++cp) {
#pragma unroll
    for (int c = 0; c < 8; ++c) {
      const unsigned short* pp = &P[(size_t)(n0 + cp * 8 + c) * MPAD];
#pragma unroll
      for (int i = 0; i < 8; ++i)
        buf[c][i * 256 + t] = pp[gd[i]];
    }
    __syncthreads();
#pragma unroll
    for (int c = 0; c < 8; ++c) {
      float* op = &out[(size_t)(n0 + cp * 8 + c) * M_PIX + p0];
#pragma unroll
      for (int i = 0; i < 8; ++i)
        op[i * 256 + t] = bf2f(buf[c][slot[i]]);
    }
    __syncthreads();
  }
}

// ---------------- Gram (unified) + fused row sums ---------------------------
__global__ __launch_bounds__(512) void k_gram(const unsigned short* __restrict__ P,
                                              const int* __restrict__ off,
                                              float* __restrict__ G,
                                              float* __restrict__ sum) {
  int l = blockIdx.y;
  long o0 = off[l], o1 = off[l + 1];
  long k0 = o0 + (long)blockIdx.x * 1024;
  if (k0 >= o1) return;
  long rem = o1 - k0;
  int ks = rem > 1024 ? 1024 : (int)rem;     // always a multiple of 512

  __shared__ unsigned short Sb[256 * LDA];
  int t = threadIdx.x, wave = t >> 6, lane = t & 63;
  int wr = (wave < 2) ? wave * 64 : 128 + (wave & 1) * 64;
  int wc = (wave >= 4) ? 128 : 0;
  bool wact = (wave < 6);

  f32x4 acc[4][8] = {};
  float rsum = 0.0f;

  for (int kk = 0; kk < ks; kk += 32) {
#pragma unroll
    for (int it = 0; it < 2; ++it) {
      int slot = t + it * 512;
      int rr = slot >> 2, gg = slot & 3;
      *(uint4*)&Sb[rr * LDA + gg * 8] =
          *(const uint4*)&P[(size_t)rr * MPAD + (size_t)(k0 + kk) + gg * 8];
    }
    __syncthreads();
    if (t < 256) {                            // fused psum: row t's 32 values
#pragma unroll
      for (int e = 0; e < 16; ++e) {
        unsigned v = *(const unsigned*)&Sb[t * LDA + e * 2];
        rsum += bf2f((unsigned short)(v & 0xFFFFu)) + bf2f((unsigned short)(v >> 16));
      }
    }
    if (wact) {
      bf16x8 bfr[8];
#pragma unroll
      for (int fj = 0; fj < 8; ++fj)
        bfr[fj] = *(const bf16x8*)&Sb[(wc + fj * 16 + (lane & 15)) * LDA + (lane >> 4) * 8];
#pragma unroll
      for (int fi = 0; fi < 4; ++fi) {
        bf16x8 afr = *(const bf16x8*)&Sb[(wr + fi * 16 + (lane & 15)) * LDA + (lane >> 4) * 8];
#pragma unroll
        for (int fj = 0; fj < 8; ++fj)
          acc[fi][fj] = __builtin_amdgcn_mfma_f32_16x16x32_bf16(afr, bfr[fj], acc[fi][fj], 0, 0, 0);
      }
    }
    __syncthreads();
  }
  float* Gl = G + ((size_t)l << 16);
  if (wact) {
#pragma unroll
    for (int fi = 0; fi < 4; ++fi)
#pragma unroll
      for (int fj = 0; fj < 8; ++fj) {
        int cc = wc + fj * 16 + (lane & 15);
#pragma unroll
        for (int rg = 0; rg < 4; ++rg) {
          int rr2 = wr + fi * 16 + (lane >> 4) * 4 + rg;
          atomicAdd(&Gl[rr2 * 256 + cc], acc[fi][fj][rg]);
        }
      }
  }
  if (t < 256) atomicAdd(&sum[l * 256 + t], rsum);
}

// ---------------- cov: read lower row-major, write TRANSPOSED in place -------
__global__ __launch_bounds__(256) void k_cov(float* __restrict__ G,
                                             const float* __restrict__ sum,
                                             const int* __restrict__ cnt,
                                             float* __restrict__ means) {
  int bid = blockIdx.x;                       // side*8 + l
  float* A = G + ((size_t)bid << 16);
  int t = threadIdx.x;
  __shared__ float mu[256];
  float fc = (float)cnt[bid];
  float m = sum[bid * 256 + t] / fmaxf(fc, 1.0f);
  mu[t] = m;
  means[bid * 256 + t] = m;
  __syncthreads();
  float rdiv = 1.0f / fmaxf(fmaxf(fc, 1.0f) - 1.0f, 1.0f);
  float mt = mu[t];
  for (int i = t; i < 256; ++i) {
    float g = A[i * 256 + t];
    A[t * 256 + i] = (g - fc * mu[i] * mt) * rdiv;
  }
}

// ---------------- fused panel step: factor + W + L21 + block-local trail -----
// One launch per panel (8 total, replaces panel+trail pairs = 15 launches).
// Phase 1: wave 0 factors the 32x32 diag in registers via shfl and computes
// W = L11^{-1}; threads 0..H2 solve L21 rows (also staged to LDS). Phase 2:
// trailing update A22 -= L21 L21^T from LDS with conflict-free float4 tiles.
__global__ __launch_bounds__(512) void k_pstep(float* __restrict__ G,
                                               float* __restrict__ Wg, int pb) {
  float* LT = G + ((size_t)blockIdx.x << 16);
  int t = threadIdx.x;
  int jbase = pb * 32;
  int H2 = 224 - jbase;
  __shared__ float Wl[32 * 36];
  __shared__ __align__(16) float L21s[32][232];

  if (t < 64) {
    int l32 = t & 31;
    float x[32];
#pragma unroll
    for (int k = 0; k < 32; ++k)
      x[k] = (k <= l32) ? LT[(size_t)(jbase + k) * 256 + jbase + l32] : 0.0f;
#pragma unroll
    for (int j = 0; j < 32; ++j) {
      float dj = __shfl(x[j], j, 64);
      float rd = 1.0f / sqrtf(dj);
      float lj = x[j] * rd;
      x[j] = lj;
#pragma unroll
      for (int k = j + 1; k < 32; ++k) {
        float lkj = __shfl(lj, k, 64);
        x[k] -= lj * lkj;
      }
    }
    if (t < 32) {
#pragma unroll
      for (int k = 0; k < 32; ++k)
        if (k <= l32) LT[(size_t)(jbase + k) * 256 + jbase + l32] = x[k];
    }
    float w[32];
#pragma unroll
    for (int k = 0; k < 32; ++k) w[k] = 0.0f;
#pragma unroll
    for (int i2 = 0; i2 < 32; ++i2) {
      float s = (i2 == l32) ? 1.0f : 0.0f;
#pragma unroll
      for (int k = 0; k < 32; ++k)
        if (k < i2) s -= __shfl(x[k], i2, 64) * w[k];
      float Lii = __shfl(x[i2], i2, 64);
      float wv = s / Lii;
      w[i2] = (i2 >= l32) ? wv : 0.0f;
    }
    if (t < 32) {
      float* Wgp = Wg + (((size_t)blockIdx.x * 8 + pb) << 10);
#pragma unroll
      for (int i2 = 0; i2 < 32; ++i2)
        if (i2 >= l32) {
          Wl[i2 * 36 + l32] = w[i2];
          Wgp[i2 * 32 + l32] = w[i2];
        }
    }
  }
  __syncthreads();

  if (t < H2) {
    int r = jbase + 32 + t;
    float a[32];
#pragma unroll
    for (int k = 0; k < 32; ++k) a[k] = LT[(size_t)(jbase + k) * 256 + r];
#pragma unroll
    for (int j = 0; j < 32; ++j) {
      float s = 0.0f;
#pragma unroll
      for (int k = 0; k < 32; ++k)
        if (k <= j) s += a[k] * Wl[j * 36 + k];
      LT[(size_t)(jbase + j) * 256 + r] = s;
      L21s[j][t] = s;
    }
  }
  __syncthreads();

  if (H2 > 0) {
    int nts = H2 >> 2;
    int ntiles = (nts * (nts + 1)) >> 1;
#pragma unroll 1
    for (int tile = t; tile < ntiles; tile += 512) {
      int ti = (int)((sqrtf(8.0f * (float)tile + 1.0f) - 1.0f) * 0.5f);
      while (((ti * (ti + 1)) >> 1) > tile) --ti;
      while ((((ti + 1) * (ti + 2)) >> 1) <= tile) ++ti;
      int tj = tile - ((ti * (ti + 1)) >> 1);
      int i0 = ti * 4, j0 = tj * 4;          // local row indices in L21s
      float acc[4][4] = {};
#pragma unroll
      for (int k = 0; k < 32; ++k) {
        float4 a = *(const float4*)&L21s[k][i0];
        float4 b = *(const float4*)&L21s[k][j0];
        acc[0][0] += a.x * b.x; acc[0][1] += a.x * b.y; acc[0][2] += a.x * b.z; acc[0][3] += a.x * b.w;
        acc[1][0] += a.y * b.x; acc[1][1] += a.y * b.y; acc[1][2] += a.y * b.z; acc[1][3] += a.y * b.w;
        acc[2][0] += a.z * b.x; acc[2][1] += a.z * b.y; acc[2][2] += a.z * b.z; acc[2][3] += a.z * b.w;
        acc[3][0] += a.w * b.x; acc[3][1] += a.w * b.y; acc[3][2] += a.w * b.z; acc[3][3] += a.w * b.w;
      }
      int gi0 = jbase + 32 + i0, gj0 = jbase + 32 + j0;
#pragma unroll
      for (int c = 0; c < 4; ++c) {
        int jg = gj0 + c;
        float* col = &LT[(size_t)jg * 256 + gi0];
#pragma unroll
        for (int rr = 0; rr < 4; ++rr)
          if (gi0 + rr >= jg) col[rr] -= acc[rr][c];
      }
    }
  }
}

// ---------------- Vinv init: diag 32-blocks from Wg (rest zero via memset) ---
__global__ __launch_bounds__(256) void k_vinit(const float* __restrict__ Wg,
                                               float* __restrict__ Vinv) {
  int l = blockIdx.x;                          // content labels 0..7
  float* V = Vinv + ((size_t)l << 16);
  const float* W = Wg + ((size_t)l * 8) * 1024;
  int t = threadIdx.x;
  for (int pb = 0; pb < 8; ++pb)
    for (int idx = t; idx < 1024; idx += 256) {
      int i = idx >> 5, j = idx & 31;
      V[(size_t)(pb * 32 + i) * 256 + pb * 32 + j] = (i >= j) ? W[pb * 1024 + idx] : 0.0f;
    }
}

// ---------------- triangular inverse doubling: X21 = -W2 * L21 * W1 ----------
// Level N merges adjacent NxN inverse blocks into 2Nx2N. 3 levels: 32->64->128->256.
template <int N>
__global__ __launch_bounds__(512) void k_vlevel(const float* __restrict__ G,
                                                float* __restrict__ Vinv) {
  constexpr int NP = 256 / (2 * N);
  constexpr int RPT = N / 32;                  // rows per thread
  constexpr int CPT = N / 16;                  // cols per thread
  int unit = blockIdx.x;
  int l = unit / NP, pair = unit % NP;
  const float* LT = G + ((size_t)l << 16);     // content L, LT col-major lower
  float* V = Vinv + ((size_t)l << 16);
  int d = pair * 2 * N;
  int t = threadIdx.x;
  int cg = t & 15, rg = t >> 4;                // 16 col-groups x 32 row-groups
  int r0 = rg * RPT, c0 = cg * CPT;

  __shared__ float Abuf[N][N + 4];             // L21 -> tmp
  __shared__ float Bbuf[N][N + 4];             // W1 -> W2

  for (int idx = t; idx < N * N; idx += 512) { // L21[r][k] = LT[(d+k)*256 + d+N+r]
    int k = idx / N, r = idx % N;
    Abuf[r][k] = LT[(size_t)(d + k) * 256 + d + N + r];
  }
  for (int idx = t; idx < N * N; idx += 512) { // W1[k][c]
    int k = idx / N, c = idx % N;
    Bbuf[k][c] = V[(size_t)(d + k) * 256 + d + c];
  }
  __syncthreads();

  float acc[RPT][CPT];
#pragma unroll
  for (int i = 0; i < RPT; ++i)
#pragma unroll
    for (int j = 0; j < CPT; ++j) acc[i][j] = 0.0f;
  for (int k = 0; k < N; ++k) {
    float av[RPT];
#pragma unroll
    for (int i = 0; i < RPT; ++i) av[i] = Abuf[r0 + i][k];
#pragma unroll
    for (int j = 0; j < CPT; ++j) {
      float bv = Bbuf[k][c0 + j];
#pragma unroll
      for (int i = 0; i < RPT; ++i) acc[i][j] += av[i] * bv;
    }
  }
  __syncthreads();
#pragma unroll
  for (int i = 0; i < RPT; ++i)                // tmp[r][c] into Abuf
#pragma unroll
    for (int j = 0; j < CPT; ++j) Abuf[r0 + i][c0 + j] = acc[i][j];
  for (int idx = t; idx < N * N; idx += 512) { // W2[r][k]
    int r = idx / N, k = idx % N;
    Bbuf[r][k] = V[(size_t)(d + N + r) * 256 + d + N + k];
  }
  __syncthreads();

#pragma unroll
  for (int i = 0; i < RPT; ++i)
#pragma unroll
    for (int j = 0; j < CPT; ++j) acc[i][j] = 0.0f;
  for (int k = 0; k < N; ++k) {
    float av[RPT];
#pragma unroll
    for (int i = 0; i < RPT; ++i) av[i] = Bbuf[r0 + i][k];
#pragma unroll
    for (int j = 0; j < CPT; ++j) {
      float bv = Abuf[k][c0 + j];
#pragma unroll
      for (int i = 0; i < RPT; ++i) acc[i][j] += av[i] * bv;
    }
  }
#pragma unroll
  for (int i = 0; i < RPT; ++i)
#pragma unroll
    for (int j = 0; j < CPT; ++j)
      V[(size_t)(d + N + r0 + i) * 256 + d + c0 + j] = -acc[i][j];
}

// ---------------- T = Ls * Vinv (tiled f32 GEMM) + bacc = T*muc partials -----
// Masked staging makes T exactly lower-triangular (upper terms have a zero
// factor). Upper tiles (tj>ti) are written as zeros; invalid labels -> I.
__global__ __launch_bounds__(256) void k_tgemm(const float* __restrict__ G,
                                               const float* __restrict__ Vinv,
                                               const float* __restrict__ means,
                                               const int* __restrict__ valid,
                                               unsigned short* __restrict__ Tb,
                                               float* __restrict__ bacc) {
  int l = blockIdx.y;
  int ti = blockIdx.x >> 2, tj = blockIdx.x & 3;
  unsigned short* Tbl = Tb + ((size_t)l << 16);
  int i0 = ti * 64, j0 = tj * 64;
  int t = threadIdx.x;
  if (!valid[l]) {
    for (int idx = t; idx < 4096; idx += 256) {
      int i = idx >> 6, j = idx & 63;
      Tbl[(size_t)(i0 + i) * 256 + j0 + j] = f2bf((i0 + i) == (j0 + j) ? 1.0f : 0.0f);
    }
    return;
  }
  if (tj > ti) {
    for (int idx = t; idx < 4096; idx += 256) {
      int i = idx >> 6, j = idx & 63;
      Tbl[(size_t)(i0 + i) * 256 + j0 + j] = 0;
    }
    return;
  }
  const float* LTs = G + ((size_t)(8 + l) << 16);  // style L, col-major lower
  const float* V = Vinv + ((size_t)l << 16);

  __shared__ float As[64][260];                // Ls rows [i0,i0+64) x k
  __shared__ __align__(16) float Bs[256][68];  // Vinv k x cols [j0,j0+64)

  for (int idx = t; idx < 64 * 256; idx += 256) {
    int k = idx >> 6, i = idx & 63;
    As[i][k] = (i0 + i >= k) ? LTs[(size_t)k * 256 + i0 + i] : 0.0f;
  }
  for (int idx = t; idx < 64 * 256; idx += 256) {
    int k = idx >> 6, j = idx & 63;
    Bs[k][j] = V[(size_t)k * 256 + j0 + j];
  }
  __syncthreads();

  int tx = t & 15, ty = t >> 4;
  float acc[4][4] = {};
  int klo = j0, khi = i0 + 64;
  for (int k = klo; k < khi; ++k) {
    float a0 = As[ty * 4 + 0][k], a1 = As[ty * 4 + 1][k];
    float a2 = As[ty * 4 + 2][k], a3 = As[ty * 4 + 3][k];
    float4 b = *(const float4*)&Bs[k][tx * 4];
    acc[0][0] += a0 * b.x; acc[0][1] += a0 * b.y; acc[0][2] += a0 * b.z; acc[0][3] += a0 * b.w;
    acc[1][0] += a1 * b.x; acc[1][1] += a1 * b.y; acc[1][2] += a1 * b.z; acc[1][3] += a1 * b.w;
    acc[2][0] += a2 * b.x; acc[2][1] += a2 * b.y; acc[2][2] += a2 * b.z; acc[2][3] += a2 * b.w;
    acc[3][0] += a3 * b.x; acc[3][1] += a3 * b.y; acc[3][2] += a3 * b.z; acc[3][3] += a3 * b.w;
  }
  float mc[4];
#pragma unroll
  for (int cc = 0; cc < 4; ++cc) mc[cc] = means[l * 256 + j0 + tx * 4 + cc];
#pragma unroll
  for (int rr = 0; rr < 4; ++rr) {
    int i = i0 + ty * 4 + rr;
    float partial = 0.0f;
#pragma unroll
    for (int cc = 0; cc < 4; ++cc) {
      Tbl[(size_t)i * 256 + j0 + tx * 4 + cc] = f2bf(acc[rr][cc]);
      partial += acc[rr][cc] * mc[cc];
    }
    atomicAdd(&bacc[l * 256 + i], partial);
  }
}

// ---------------- bvec = mus - bacc (0 if invalid) ---------------------------
__global__ __launch_bounds__(256) void k_bvec(const float* __restrict__ means,
                                              const float* __restrict__ bacc,
                                              const int* __restrict__ valid,
                                              float* __restrict__ bvec) {
  int l = blockIdx.x, i = threadIdx.x;
  bvec[l * 256 + i] = valid[l] ? (means[(8 + l) * 256 + i] - bacc[l * 256 + i]) : 0.0f;
}

// ---------------- out = T_l * x + b_l on packed pixels (in place in P) -------
__global__ __launch_bounds__(256) void k_outgemm(unsigned short* __restrict__ P,
                                                 const unsigned short* __restrict__ Tb,
                                                 const float* __restrict__ bvec,
                                                 const int* __restrict__ off) {
  long px0 = (long)blockIdx.x * 128;
  if (px0 >= off[8]) return;
  int l = 0;
  while (l < 7 && px0 >= off[l + 1]) ++l;
  const unsigned short* Tl = Tb + ((size_t)l << 16);

  __shared__ unsigned short As[256 * LDA];
  __shared__ unsigned short Bs[128 * LDA];
  __shared__ float bsh[256];

  int t = threadIdx.x, wave = t >> 6, lane = t & 63;
  int wrow = wave * 64;
  bsh[t] = bvec[l * 256 + t];

  f32x4 acc[4][8] = {};

  for (int kk = 0; kk < 256; kk += 32) {
#pragma unroll
    for (int it = 0; it < 4; ++it) {            // A: 256 rows x 32 k
      int slot = t + it * 256;
      int rr = slot >> 2, gg = slot & 3;
      *(uint4*)&As[rr * LDA + gg * 8] = *(const uint4*)&Tl[rr * 256 + kk + gg * 8];
    }
#pragma unroll
    for (int it = 0; it < 2; ++it) {            // B: transpose-stage 32k x 128px
      int slot = t + it * 256;
      int pg = slot & 15, kr = slot >> 4;
      uint4 v = *(const uint4*)&P[(size_t)(kk + kr) * MPAD + px0 + pg * 8];
      const unsigned short* vs = (const unsigned short*)&v;
      int krs = kr ^ ((pg & 3) << 3);           // k-block XOR swizzle (bank spread)
#pragma unroll
      for (int e = 0; e < 8; ++e) Bs[(pg * 8 + e) * LDA + krs] = vs[e];
    }
    __syncthreads();
    if (kk < wrow + 64) {                       // T is lower-triangular: skip dead k-tiles
      bf16x8 bfr[8];
#pragma unroll
      for (int fj = 0; fj < 8; ++fj) {
        int px = fj * 16 + (lane & 15);
        int gs = (lane >> 4) ^ ((px >> 3) & 3);
        bfr[fj] = *(const bf16x8*)&Bs[px * LDA + gs * 8];
      }
#pragma unroll
      for (int fi = 0; fi < 4; ++fi) {
        if (wrow + fi * 16 + 15 >= kk) {
          bf16x8 afr = *(const bf16x8*)&As[(wrow + fi * 16 + (lane & 15)) * LDA + (lane >> 4) * 8];
#pragma unroll
          for (int fj = 0; fj < 8; ++fj)
            acc[fi][fj] = __builtin_amdgcn_mfma_f32_16x16x32_bf16(afr, bfr[fj], acc[fi][fj], 0, 0, 0);
        }
      }
    }
    __syncthreads();
  }
#pragma unroll
  for (int fi = 0; fi < 4; ++fi)
#pragma unroll
    for (int fj = 0; fj < 8; ++fj) {
      long p = px0 + fj * 16 + (lane & 15);
#pragma unroll
      for (int rg = 0; rg < 4; ++rg) {
        int rr = wrow + fi * 16 + (lane >> 4) * 4 + rg;
        float v = acc[fi][fj][rg] + bsh[rr];
        P[(size_t)rr * MPAD + p] = f2bf(v);
      }
    }
}

// =============================================================================
extern "C" void kernel_launch(void* const* d_in, const int* in_sizes, int n_in,
                              void* d_out, int out_size, void* d_ws, size_t ws_size,
                              hipStream_t stream) {
  const float* cfeat = (const float*)d_in[0];
  const float* sfeat = (const float*)d_in[1];
  const int* seg_c   = (const int*)d_in[2];
  const int* seg_s   = (const int*)d_in[3];

  char* ws = (char*)d_ws;
  size_t o = 0;
  auto take = [&](size_t b) { size_t r = o; o += (b + 255) & ~(size_t)255; return r; };

  unsigned short* P  = (unsigned short*)(ws + take((size_t)NCH * MPAD * 2));
  size_t zero_b = o;
  float* G           = (float*)(ws + take((size_t)2 * 8 * 65536 * 4));
  float* Vinv        = (float*)(ws + take((size_t)8 * 65536 * 4));
  float* sum         = (float*)(ws + take((size_t)2 * 8 * 256 * 4));
  float* bacc        = (float*)(ws + take((size_t)8 * 256 * 4));
  int*   hist        = (int*)(ws + take((size_t)2 * 128 * 8 * 4));
  size_t zero_e = o;
  unsigned short* Tb = (unsigned short*)(ws + take((size_t)8 * 65536 * 2));
  float* Wg          = (float*)(ws + take((size_t)16 * 8 * 1024 * 4));
  int*   dst         = (int*)(ws + take((size_t)2 * M_PIX * 4));
  float* means       = (float*)(ws + take((size_t)2 * 8 * 256 * 4));
  float* bvec        = (float*)(ws + take((size_t)8 * 256 * 4));
  int*   base        = (int*)(ws + take((size_t)2 * 128 * 8 * 4));
  int*   off         = (int*)(ws + take((size_t)2 * 9 * 4));
  int*   cnt         = (int*)(ws + take((size_t)2 * 8 * 4));
  int*   valid       = (int*)(ws + take((size_t)8 * 4));
  (void)ws_size; (void)n_in; (void)in_sizes; (void)out_size;

  hipMemsetAsync(ws + zero_b, 0, zero_e - zero_b, stream);

  k_hist<<<dim3(128), dim3(256), 0, stream>>>(seg_c, seg_s, hist);
  k_scan<<<dim3(1), dim3(256), 0, stream>>>(hist, base, off, cnt, valid);
  k_rank<<<dim3(128), dim3(256), 0, stream>>>(seg_c, seg_s, base, dst);

  // style (side 1) first, then content (side 0); P is reused, stream-serial.
  for (int s = 1; s >= 0; --s) {
    const float* feat = s ? sfeat : cfeat;
    const int* seg = s ? seg_s : seg_c;
    k_padzero<<<dim3(9), dim3(256), 0, stream>>>(P, off + s * 9, cnt + s * 8);
    k_pack<<<dim3(128, 8), dim3(256), 0, stream>>>(feat, seg, dst + (size_t)s * M_PIX,
                                                   base + s * 1024, P);
    k_gram<<<dim3(260, 8), dim3(512), 0, stream>>>(P, off + s * 9, G + (size_t)s * 8 * 65536,
                                                   sum + (size_t)s * 8 * 256);
  }

  k_cov<<<dim3(16), dim3(256), 0, stream>>>(G, sum, cnt, means);
  for (int pb = 0; pb < 8; ++pb)
    k_pstep<<<dim3(16), dim3(512), 0, stream>>>(G, Wg, pb);
  k_vinit<<<dim3(8), dim3(256), 0, stream>>>(Wg, Vinv);
  k_vlevel<32><<<dim3(32), dim3(512), 0, stream>>>(G, Vinv);
  k_vlevel<64><<<dim3(16), dim3(512), 0, stream>>>(G, Vinv);
  k_vlevel<128><<<dim3(8), dim3(512), 0, stream>>>(G, Vinv);
  k_tgemm<<<dim3(16, 8), dim3(256), 0, stream>>>(G, Vinv, means, valid, Tb, bacc);
  k_bvec<<<dim3(8), dim3(256), 0, stream>>>(means, bacc, valid, bvec);
  k_outgemm<<<dim3(2080), dim3(256), 0, stream>>>(P, Tb, bvec, off);
  k_unpack<<<dim3(128, 8), dim3(256), 0, stream>>>(P, seg_c, dst, base, (float*)d_out);
}

// Round 10
// 1144.110 us; speedup vs baseline: 1.5163x; 1.5163x over previous
//
#include <hip/hip_runtime.h>

#define NCH   256
#define M_PIX 262144
#define MPAD  266240   // 520*512 ; >= M_PIX + 8*512 worst-case alignment pad
#define LDA   40       // padded LDS leading dim (bf16 elements) for 32-wide k tiles

typedef short bf16x8 __attribute__((ext_vector_type(8)));
typedef float f32x4  __attribute__((ext_vector_type(4)));

__device__ __forceinline__ unsigned short f2bf(float f) {
  union { float f; unsigned u; } v; v.f = f;
  unsigned r = v.u + 0x7FFFu + ((v.u >> 16) & 1u);
  return (unsigned short)(r >> 16);
}
__device__ __forceinline__ float bf2f(unsigned short h) {
  union { unsigned u; float f; } v; v.u = ((unsigned)h) << 16;
  return v.f;
}

// ---------------- histogram: per-2048-pixel-block label counts, both segs ----
__global__ __launch_bounds__(256) void k_hist(const int* __restrict__ seg_c,
                                              const int* __restrict__ seg_s,
                                              int* __restrict__ hist) {
  __shared__ int h[16];
  int t = threadIdx.x;
  if (t < 16) h[t] = 0;
  __syncthreads();
  int p0 = blockIdx.x * 2048 + t * 8;
#pragma unroll
  for (int e = 0; e < 8; ++e) {
    atomicAdd(&h[seg_c[p0 + e] & 7], 1);
    atomicAdd(&h[8 + (seg_s[p0 + e] & 7)], 1);
  }
  __syncthreads();
  if (t < 8) hist[blockIdx.x * 8 + t] = h[t];
  else if (t < 16) hist[1024 + blockIdx.x * 8 + (t - 8)] = h[t];
}

// ---------------- scan: totals, 512-aligned offsets, per-block bases, valid --
__global__ __launch_bounds__(256) void k_scan(const int* __restrict__ hist,
                                              int* __restrict__ base,
                                              int* __restrict__ off,
                                              int* __restrict__ cnt,
                                              int* __restrict__ valid) {
  __shared__ int lh[2048];
  __shared__ int tot[16];
  __shared__ int loff[2][9];
  int t = threadIdx.x;
  for (int i = t; i < 2048; i += 256) lh[i] = hist[i];
  __syncthreads();
  if (t < 16) {
    int s = t >> 3, l = t & 7, acc = 0;
    for (int b = 0; b < 128; ++b) acc += lh[s * 1024 + b * 8 + l];
    tot[t] = acc;
  }
  __syncthreads();
  if (t < 2) {
    int run = 0;
    for (int l = 0; l < 8; ++l) {
      loff[t][l] = run;
      run = (run + tot[t * 8 + l] + 511) & ~511;
    }
    loff[t][8] = run;
    for (int l = 0; l < 9; ++l) off[t * 9 + l] = loff[t][l];
    for (int l = 0; l < 8; ++l) cnt[t * 8 + l] = tot[t * 8 + l];
  }
  __syncthreads();
  if (t < 8) {
    long nc = tot[t], ns = tot[8 + t];
    valid[t] = (nc > 10 && ns > 10 && nc < 100 * ns && ns < 100 * nc) ? 1 : 0;
  }
  if (t < 16) {
    int s = t >> 3, l = t & 7;
    int run = loff[s][l];
    for (int b = 0; b < 128; ++b) {
      base[s * 1024 + b * 8 + l] = run;
      run += lh[s * 1024 + b * 8 + l];
    }
  }
}

// ---------------- rank: stable per-pixel destination slot (counting sort) ----
__global__ __launch_bounds__(256) void k_rank(const int* __restrict__ seg_c,
                                              const int* __restrict__ seg_s,
                                              const int* __restrict__ base,
                                              int* __restrict__ dst) {
  __shared__ int sc[8 * 272];
  __shared__ int rb[256 * 8];
  __shared__ int bb[8];
  int t = threadIdx.x;
  for (int s = 0; s < 2; ++s) {
    const int* seg = s ? seg_s : seg_c;
    const int* bas = base + s * 1024 + blockIdx.x * 8;
    int* dd = dst + (size_t)s * M_PIX;
    int p0 = blockIdx.x * 2048 + t * 8;
    unsigned pk2 = 0, cpk = 0;
#pragma unroll
    for (int e = 0; e < 8; ++e) {
      int lb = seg[p0 + e] & 7;
      pk2 |= (unsigned)lb << (3 * e);
      cpk += 1u << (4 * lb);
    }
#pragma unroll
    for (int lq = 0; lq < 8; ++lq) sc[lq * 272 + t] = (int)((cpk >> (4 * lq)) & 15u);
    if (t < 8) bb[t] = bas[t];
    __syncthreads();
    for (int d = 1; d < 256; d <<= 1) {
      int v[8];
#pragma unroll
      for (int lq = 0; lq < 8; ++lq)
        v[lq] = sc[lq * 272 + t] + ((t >= d) ? sc[lq * 272 + t - d] : 0);
      __syncthreads();
#pragma unroll
      for (int lq = 0; lq < 8; ++lq) sc[lq * 272 + t] = v[lq];
      __syncthreads();
    }
#pragma unroll
    for (int lq = 0; lq < 8; ++lq)
      rb[t * 8 + lq] = bb[lq] + sc[lq * 272 + t] - (int)((cpk >> (4 * lq)) & 15u);
#pragma unroll
    for (int e = 0; e < 8; ++e) {
      int lb = (int)((pk2 >> (3 * e)) & 7u);
      int dpos = rb[t * 8 + lb]++;
      dd[p0 + e] = dpos;
    }
    __syncthreads();
  }
}

// ---------------- zero the alignment pads of P -------------------------------
__global__ __launch_bounds__(256) void k_padzero(unsigned short* __restrict__ P,
                                                 const int* __restrict__ off,
                                                 const int* __restrict__ cnt) {
  int l = blockIdx.x;
  int c0, c1;
  if (l < 8) { c0 = off[l] + cnt[l]; c1 = off[l + 1]; }
  else       { c0 = off[8];          c1 = MPAD; }
  int w = c1 - c0;
  if (w <= 0) return;
  for (int r = 0; r < 256; ++r)
    for (int cc = threadIdx.x; cc < w; cc += 256)
      P[(size_t)r * MPAD + c0 + cc] = 0;
}

// ---------------- pack: coalesced-both-sides via LDS local sort --------------
__global__ __launch_bounds__(256) void k_pack(const float* __restrict__ feat,
                                              const int* __restrict__ seg,
                                              const int* __restrict__ dst,
                                              const int* __restrict__ base,
                                              unsigned short* __restrict__ P) {
  int b = blockIdx.x, g = blockIdx.y, t = threadIdx.x;
  int p0 = b * 2048;
  __shared__ unsigned short buf[8][2048];
  __shared__ int h[8], lbase[9], gbase[8];
  if (t < 8) { h[t] = 0; gbase[t] = base[b * 8 + t]; }
  __syncthreads();
  int lb[8], slot[8], gd[8];
#pragma unroll
  for (int i = 0; i < 8; ++i) {
    lb[i] = seg[p0 + i * 256 + t] & 7;
    atomicAdd(&h[lb[i]], 1);
  }
  __syncthreads();
  if (t == 0) {
    int run = 0;
    for (int l = 0; l < 8; ++l) { lbase[l] = run; run += h[l]; }
    lbase[8] = run;
  }
  __syncthreads();
#pragma unroll
  for (int i = 0; i < 8; ++i)
    slot[i] = lbase[lb[i]] + (dst[p0 + i * 256 + t] - gbase[lb[i]]);
#pragma unroll
  for (int i = 0; i < 8; ++i) {
    int q = i * 256 + t;
    int l = 0;
    while (l < 7 && q >= lbase[l + 1]) ++l;
    gd[i] = gbase[l] + q - lbase[l];
  }
  int n0 = g * 32;
#pragma unroll 1
  for (int cp = 0; cp < 4; ++cp) {
#pragma unroll
    for (int c = 0; c < 8; ++c) {
      const float* fp = &feat[(size_t)(n0 + cp * 8 + c) * M_PIX + p0];
#pragma unroll
      for (int i = 0; i < 8; ++i)
        buf[c][slot[i]] = f2bf(fp[i * 256 + t]);
    }
    __syncthreads();
#pragma unroll
    for (int c = 0; c < 8; ++c) {
      unsigned short* pp = &P[(size_t)(n0 + cp * 8 + c) * MPAD];
#pragma unroll
      for (int i = 0; i < 8; ++i)
        pp[gd[i]] = buf[c][i * 256 + t];
    }
    __syncthreads();
  }
}

// ---------------- unpack: mirrored (contiguous reads, coalesced f32 writes) --
__global__ __launch_bounds__(256) void k_unpack(const unsigned short* __restrict__ P,
                                                const int* __restrict__ seg,
                                                const int* __restrict__ dst,
                                                const int* __restrict__ base,
                                                float* __restrict__ out) {
  int b = blockIdx.x, g = blockIdx.y, t = threadIdx.x;
  int p0 = b * 2048;
  __shared__ unsigned short buf[8][2048];
  __shared__ int h[8], lbase[9], gbase[8];
  if (t < 8) { h[t] = 0; gbase[t] = base[b * 8 + t]; }
  __syncthreads();
  int lb[8], slot[8], gd[8];
#pragma unroll
  for (int i = 0; i < 8; ++i) {
    lb[i] = seg[p0 + i * 256 + t] & 7;
    atomicAdd(&h[lb[i]], 1);
  }
  __syncthreads();
  if (t == 0) {
    int run = 0;
    for (int l = 0; l < 8; ++l) { lbase[l] = run; run += h[l]; }
    lbase[8] = run;
  }
  __syncthreads();
#pragma unroll
  for (int i = 0; i < 8; ++i)
    slot[i] = lbase[lb[i]] + (dst[p0 + i * 256 + t] - gbase[lb[i]]);
#pragma unroll
  for (int i = 0; i < 8; ++i) {
    int q = i * 256 + t;
    int l = 0;
    while (l < 7 && q >= lbase[l + 1]) ++l;
    gd[i] = gbase[l] + q - lbase[l];
  }
  int n0 = g * 32;
#pragma unroll 1
  for (int cp = 0; cp < 4; ++cp) {
#pragma unroll
    for (int c = 0; c < 8; ++c) {
      const unsigned short* pp = &P[(size_t)(n0 + cp * 8 + c) * MPAD];
#pragma unroll
      for (int i = 0; i < 8; ++i)
        buf[c][i * 256 + t] = pp[gd[i]];
    }
    __syncthreads();
#pragma unroll
    for (int c = 0; c < 8; ++c) {
      float* op = &out[(size_t)(n0 + cp * 8 + c) * M_PIX + p0];
#pragma unroll
      for (int i = 0; i < 8; ++i)
        op[i * 256 + t] = bf2f(buf[c][slot[i]]);
    }
    __syncthreads();
  }
}

// ---------------- Gram (unified) + fused row sums ---------------------------
__global__ __launch_bounds__(512) void k_gram(const unsigned short* __restrict__ P,
                                              const int* __restrict__ off,
                                              float* __restrict__ G,
                                              float* __restrict__ sum) {
  int l = blockIdx.y;
  long o0 = off[l], o1 = off[l + 1];
  long k0 = o0 + (long)blockIdx.x * 1024;
  if (k0 >= o1) return;
  long rem = o1 - k0;
  int ks = rem > 1024 ? 1024 : (int)rem;     // always a multiple of 512

  __shared__ unsigned short Sb[256 * LDA];
  int t = threadIdx.x, wave = t >> 6, lane = t & 63;
  int wr = (wave < 2) ? wave * 64 : 128 + (wave & 1) * 64;
  int wc = (wave >= 4) ? 128 : 0;
  bool wact = (wave < 6);

  f32x4 acc[4][8] = {};
  float rsum = 0.0f;

  for (int kk = 0; kk < ks; kk += 32) {
#pragma unroll
    for (int it = 0; it < 2; ++it) {
      int slot = t + it * 512;
      int rr = slot >> 2, gg = slot & 3;
      *(uint4*)&Sb[rr * LDA + gg * 8] =
          *(const uint4*)&P[(size_t)rr * MPAD + (size_t)(k0 + kk) + gg * 8];
    }
    __syncthreads();
    if (t < 256) {                            // fused psum: row t's 32 values
#pragma unroll
      for (int e = 0; e < 16; ++e) {
        unsigned v = *(const unsigned*)&Sb[t * LDA + e * 2];
        rsum += bf2f((unsigned short)(v & 0xFFFFu)) + bf2f((unsigned short)(v >> 16));
      }
    }
    if (wact) {
      bf16x8 bfr[8];
#pragma unroll
      for (int fj = 0; fj < 8; ++fj)
        bfr[fj] = *(const bf16x8*)&Sb[(wc + fj * 16 + (lane & 15)) * LDA + (lane >> 4) * 8];
#pragma unroll
      for (int fi = 0; fi < 4; ++fi) {
        bf16x8 afr = *(const bf16x8*)&Sb[(wr + fi * 16 + (lane & 15)) * LDA + (lane >> 4) * 8];
#pragma unroll
        for (int fj = 0; fj < 8; ++fj)
          acc[fi][fj] = __builtin_amdgcn_mfma_f32_16x16x32_bf16(afr, bfr[fj], acc[fi][fj], 0, 0, 0);
      }
    }
    __syncthreads();
  }
  float* Gl = G + ((size_t)l << 16);
  if (wact) {
#pragma unroll
    for (int fi = 0; fi < 4; ++fi)
#pragma unroll
      for (int fj = 0; fj < 8; ++fj) {
        int cc = wc + fj * 16 + (lane & 15);
#pragma unroll
        for (int rg = 0; rg < 4; ++rg) {
          int rr2 = wr + fi * 16 + (lane >> 4) * 4 + rg;
          atomicAdd(&Gl[rr2 * 256 + cc], acc[fi][fj][rg]);
        }
      }
  }
  if (t < 256) atomicAdd(&sum[l * 256 + t], rsum);
}

// ---------------- cov: read lower row-major, write TRANSPOSED in place -------
__global__ __launch_bounds__(256) void k_cov(float* __restrict__ G,
                                             const float* __restrict__ sum,
                                             const int* __restrict__ cnt,
                                             float* __restrict__ means) {
  int bid = blockIdx.x;                       // side*8 + l
  float* A = G + ((size_t)bid << 16);
  int t = threadIdx.x;
  __shared__ float mu[256];
  float fc = (float)cnt[bid];
  float m = sum[bid * 256 + t] / fmaxf(fc, 1.0f);
  mu[t] = m;
  means[bid * 256 + t] = m;
  __syncthreads();
  float rdiv = 1.0f / fmaxf(fmaxf(fc, 1.0f) - 1.0f, 1.0f);
  float mt = mu[t];
  for (int i = t; i < 256; ++i) {
    float g = A[i * 256 + t];
    A[t * 256 + i] = (g - fc * mu[i] * mt) * rdiv;
  }
}

// ---------------- panel step: factor 32x32 diag + W=L11^{-1} + L21 ----------
// (round-8 structure restored: trailing update stays in the WIDE k_trail)
__global__ __launch_bounds__(256) void k_panel(float* __restrict__ G,
                                               float* __restrict__ Wg,
                                               int pb) {
  float* LT = G + ((size_t)blockIdx.x << 16);
  int t = threadIdx.x;
  int jbase = pb * 32;
  int H2 = 224 - jbase;
  __shared__ float Wl[32 * 36];

  if (t < 64) {
    int l32 = t & 31;
    float x[32];
#pragma unroll
    for (int k = 0; k < 32; ++k)
      x[k] = (k <= l32) ? LT[(size_t)(jbase + k) * 256 + jbase + l32] : 0.0f;
#pragma unroll
    for (int j = 0; j < 32; ++j) {
      float dj = __shfl(x[j], j, 64);
      float rd = 1.0f / sqrtf(dj);
      float lj = x[j] * rd;
      x[j] = lj;
#pragma unroll
      for (int k = j + 1; k < 32; ++k) {
        float lkj = __shfl(lj, k, 64);
        x[k] -= lj * lkj;
      }
    }
    if (t < 32) {
#pragma unroll
      for (int k = 0; k < 32; ++k)
        if (k <= l32) LT[(size_t)(jbase + k) * 256 + jbase + l32] = x[k];
    }
    float w[32];
#pragma unroll
    for (int k = 0; k < 32; ++k) w[k] = 0.0f;
#pragma unroll
    for (int i2 = 0; i2 < 32; ++i2) {
      float s = (i2 == l32) ? 1.0f : 0.0f;
#pragma unroll
      for (int k = 0; k < 32; ++k)
        if (k < i2) s -= __shfl(x[k], i2, 64) * w[k];
      float Lii = __shfl(x[i2], i2, 64);
      float wv = s / Lii;
      w[i2] = (i2 >= l32) ? wv : 0.0f;
    }
    if (t < 32) {
      float* Wgp = Wg + (((size_t)blockIdx.x * 8 + pb) << 10);
#pragma unroll
      for (int i2 = 0; i2 < 32; ++i2)
        if (i2 >= l32) {
          Wl[i2 * 36 + l32] = w[i2];
          Wgp[i2 * 32 + l32] = w[i2];
        }
    }
  }
  __syncthreads();

  if (t < H2) {
    int r = jbase + 32 + t;
    float a[32];
#pragma unroll
    for (int k = 0; k < 32; ++k) a[k] = LT[(size_t)(jbase + k) * 256 + r];
#pragma unroll
    for (int j = 0; j < 32; ++j) {
      float s = 0.0f;
#pragma unroll
      for (int k = 0; k < 32; ++k)
        if (k <= j) s += a[k] * Wl[j * 36 + k];
      LT[(size_t)(jbase + j) * 256 + r] = s;
    }
  }
}

// ---------------- trailing step: A22 -= L21 * L21^T (wide, 64x64 tiles) ------
__global__ __launch_bounds__(256) void k_trail(float* __restrict__ G, int pb) {
  int jbase = pb * 32;
  int H2 = 224 - jbase;
  int nts2 = (H2 + 63) >> 6;
  int y = blockIdx.y;
  if (y >= (nts2 * (nts2 + 1)) >> 1) return;
  int ti = 0;
  while ((((ti + 1) * (ti + 2)) >> 1) <= y) ++ti;
  int tj = y - ((ti * (ti + 1)) >> 1);
  float* LT = G + ((size_t)blockIdx.x << 16);
  int i0 = jbase + 32 + ti * 64;
  int j0 = jbase + 32 + tj * 64;

  __shared__ float Li[32][64];
  __shared__ float Lj[32][64];
  int t = threadIdx.x;
  for (int idx = t; idx < 2048; idx += 256) {
    int k = idx >> 6, r = idx & 63;
    Li[k][r] = (i0 + r < 256) ? LT[(size_t)(jbase + k) * 256 + i0 + r] : 0.0f;
    Lj[k][r] = (j0 + r < 256) ? LT[(size_t)(jbase + k) * 256 + j0 + r] : 0.0f;
  }
  __syncthreads();

  int tx = t & 15, ty = t >> 4;
  float acc[4][4] = {};
#pragma unroll
  for (int k = 0; k < 32; ++k) {
    float4 a = *(const float4*)&Li[k][ty * 4];
    float4 b = *(const float4*)&Lj[k][tx * 4];
    acc[0][0] += a.x * b.x; acc[0][1] += a.x * b.y; acc[0][2] += a.x * b.z; acc[0][3] += a.x * b.w;
    acc[1][0] += a.y * b.x; acc[1][1] += a.y * b.y; acc[1][2] += a.y * b.z; acc[1][3] += a.y * b.w;
    acc[2][0] += a.z * b.x; acc[2][1] += a.z * b.y; acc[2][2] += a.z * b.z; acc[2][3] += a.z * b.w;
    acc[3][0] += a.w * b.x; acc[3][1] += a.w * b.y; acc[3][2] += a.w * b.z; acc[3][3] += a.w * b.w;
  }
#pragma unroll
  for (int jj = 0; jj < 4; ++jj) {
    int j = j0 + tx * 4 + jj;
    if (j >= 256) continue;
    float* col = &LT[(size_t)j * 256 + i0 + ty * 4];
#pragma unroll
    for (int ii = 0; ii < 4; ++ii) {
      int i = i0 + ty * 4 + ii;
      if (i < 256 && i >= j) col[ii] -= acc[ii][jj];
    }
  }
}

// ---------------- Vinv init: diag 32-blocks from Wg (rest zero via memset) ---
__global__ __launch_bounds__(256) void k_vinit(const float* __restrict__ Wg,
                                               float* __restrict__ Vinv) {
  int l = blockIdx.x;                          // content labels 0..7
  float* V = Vinv + ((size_t)l << 16);
  const float* W = Wg + ((size_t)l * 8) * 1024;
  int t = threadIdx.x;
  for (int pb = 0; pb < 8; ++pb)
    for (int idx = t; idx < 1024; idx += 256) {
      int i = idx >> 5, j = idx & 31;
      V[(size_t)(pb * 32 + i) * 256 + pb * 32 + j] = (i >= j) ? W[pb * 1024 + idx] : 0.0f;
    }
}

// ---------------- triangular inverse doubling: X21 = -W2 * L21 * W1 ----------
template <int N>
__global__ __launch_bounds__(512) void k_vlevel(const float* __restrict__ G,
                                                float* __restrict__ Vinv) {
  constexpr int NP = 256 / (2 * N);
  constexpr int RPT = N / 32;                  // rows per thread
  constexpr int CPT = N / 16;                  // cols per thread
  int unit = blockIdx.x;
  int l = unit / NP, pair = unit % NP;
  const float* LT = G + ((size_t)l << 16);     // content L, LT col-major lower
  float* V = Vinv + ((size_t)l << 16);
  int d = pair * 2 * N;
  int t = threadIdx.x;
  int cg = t & 15, rg = t >> 4;                // 16 col-groups x 32 row-groups
  int r0 = rg * RPT, c0 = cg * CPT;

  __shared__ float Abuf[N][N + 4];             // L21 -> tmp
  __shared__ float Bbuf[N][N + 4];             // W1 -> W2

  for (int idx = t; idx < N * N; idx += 512) { // L21[r][k] = LT[(d+k)*256 + d+N+r]
    int k = idx / N, r = idx % N;
    Abuf[r][k] = LT[(size_t)(d + k) * 256 + d + N + r];
  }
  for (int idx = t; idx < N * N; idx += 512) { // W1[k][c]
    int k = idx / N, c = idx % N;
    Bbuf[k][c] = V[(size_t)(d + k) * 256 + d + c];
  }
  __syncthreads();

  float acc[RPT][CPT];
#pragma unroll
  for (int i = 0; i < RPT; ++i)
#pragma unroll
    for (int j = 0; j < CPT; ++j) acc[i][j] = 0.0f;
  for (int k = 0; k < N; ++k) {
    float av[RPT];
#pragma unroll
    for (int i = 0; i < RPT; ++i) av[i] = Abuf[r0 + i][k];
#pragma unroll
    for (int j = 0; j < CPT; ++j) {
      float bv = Bbuf[k][c0 + j];
#pragma unroll
      for (int i = 0; i < RPT; ++i) acc[i][j] += av[i] * bv;
    }
  }
  __syncthreads();
#pragma unroll
  for (int i = 0; i < RPT; ++i)                // tmp[r][c] into Abuf
#pragma unroll
    for (int j = 0; j < CPT; ++j) Abuf[r0 + i][c0 + j] = acc[i][j];
  for (int idx = t; idx < N * N; idx += 512) { // W2[r][k]
    int r = idx / N, k = idx % N;
    Bbuf[r][k] = V[(size_t)(d + N + r) * 256 + d + N + k];
  }
  __syncthreads();

#pragma unroll
  for (int i = 0; i < RPT; ++i)
#pragma unroll
    for (int j = 0; j < CPT; ++j) acc[i][j] = 0.0f;
  for (int k = 0; k < N; ++k) {
    float av[RPT];
#pragma unroll
    for (int i = 0; i < RPT; ++i) av[i] = Bbuf[r0 + i][k];
#pragma unroll
    for (int j = 0; j < CPT; ++j) {
      float bv = Abuf[k][c0 + j];
#pragma unroll
      for (int i = 0; i < RPT; ++i) acc[i][j] += av[i] * bv;
    }
  }
#pragma unroll
  for (int i = 0; i < RPT; ++i)
#pragma unroll
    for (int j = 0; j < CPT; ++j)
      V[(size_t)(d + N + r0 + i) * 256 + d + c0 + j] = -acc[i][j];
}

// ---------------- T = Ls * Vinv (tiled f32 GEMM) + bacc = T*muc partials -----
__global__ __launch_bounds__(256) void k_tgemm(const float* __restrict__ G,
                                               const float* __restrict__ Vinv,
                                               const float* __restrict__ means,
                                               const int* __restrict__ valid,
                                               unsigned short* __restrict__ Tb,
                                               float* __restrict__ bacc) {
  int l = blockIdx.y;
  int ti = blockIdx.x >> 2, tj = blockIdx.x & 3;
  unsigned short* Tbl = Tb + ((size_t)l << 16);
  int i0 = ti * 64, j0 = tj * 64;
  int t = threadIdx.x;
  if (!valid[l]) {
    for (int idx = t; idx < 4096; idx += 256) {
      int i = idx >> 6, j = idx & 63;
      Tbl[(size_t)(i0 + i) * 256 + j0 + j] = f2bf((i0 + i) == (j0 + j) ? 1.0f : 0.0f);
    }
    return;
  }
  if (tj > ti) {
    for (int idx = t; idx < 4096; idx += 256) {
      int i = idx >> 6, j = idx & 63;
      Tbl[(size_t)(i0 + i) * 256 + j0 + j] = 0;
    }
    return;
  }
  const float* LTs = G + ((size_t)(8 + l) << 16);  // style L, col-major lower
  const float* V = Vinv + ((size_t)l << 16);

  __shared__ float As[64][260];                // Ls rows [i0,i0+64) x k
  __shared__ __align__(16) float Bs[256][68];  // Vinv k x cols [j0,j0+64)

  for (int idx = t; idx < 64 * 256; idx += 256) {
    int k = idx >> 6, i = idx & 63;
    As[i][k] = (i0 + i >= k) ? LTs[(size_t)k * 256 + i0 + i] : 0.0f;
  }
  for (int idx = t; idx < 64 * 256; idx += 256) {
    int k = idx >> 6, j = idx & 63;
    Bs[k][j] = V[(size_t)k * 256 + j0 + j];
  }
  __syncthreads();

  int tx = t & 15, ty = t >> 4;
  float acc[4][4] = {};
  int klo = j0, khi = i0 + 64;
  for (int k = klo; k < khi; ++k) {
    float a0 = As[ty * 4 + 0][k], a1 = As[ty * 4 + 1][k];
    float a2 = As[ty * 4 + 2][k], a3 = As[ty * 4 + 3][k];
    float4 b = *(const float4*)&Bs[k][tx * 4];
    acc[0][0] += a0 * b.x; acc[0][1] += a0 * b.y; acc[0][2] += a0 * b.z; acc[0][3] += a0 * b.w;
    acc[1][0] += a1 * b.x; acc[1][1] += a1 * b.y; acc[1][2] += a1 * b.z; acc[1][3] += a1 * b.w;
    acc[2][0] += a2 * b.x; acc[2][1] += a2 * b.y; acc[2][2] += a2 * b.z; acc[2][3] += a2 * b.w;
    acc[3][0] += a3 * b.x; acc[3][1] += a3 * b.y; acc[3][2] += a3 * b.z; acc[3][3] += a3 * b.w;
  }
  float mc[4];
#pragma unroll
  for (int cc = 0; cc < 4; ++cc) mc[cc] = means[l * 256 + j0 + tx * 4 + cc];
#pragma unroll
  for (int rr = 0; rr < 4; ++rr) {
    int i = i0 + ty * 4 + rr;
    float partial = 0.0f;
#pragma unroll
    for (int cc = 0; cc < 4; ++cc) {
      Tbl[(size_t)i * 256 + j0 + tx * 4 + cc] = f2bf(acc[rr][cc]);
      partial += acc[rr][cc] * mc[cc];
    }
    atomicAdd(&bacc[l * 256 + i], partial);
  }
}

// ---------------- bvec = mus - bacc (0 if invalid) ---------------------------
__global__ __launch_bounds__(256) void k_bvec(const float* __restrict__ means,
                                              const float* __restrict__ bacc,
                                              const int* __restrict__ valid,
                                              float* __restrict__ bvec) {
  int l = blockIdx.x, i = threadIdx.x;
  bvec[l * 256 + i] = valid[l] ? (means[(8 + l) * 256 + i] - bacc[l * 256 + i]) : 0.0f;
}

// ---------------- out = T_l * x + b_l on packed pixels (in place in P) -------
__global__ __launch_bounds__(256) void k_outgemm(unsigned short* __restrict__ P,
                                                 const unsigned short* __restrict__ Tb,
                                                 const float* __restrict__ bvec,
                                                 const int* __restrict__ off) {
  long px0 = (long)blockIdx.x * 128;
  if (px0 >= off[8]) return;
  int l = 0;
  while (l < 7 && px0 >= off[l + 1]) ++l;
  const unsigned short* Tl = Tb + ((size_t)l << 16);

  __shared__ unsigned short As[256 * LDA];
  __shared__ unsigned short Bs[128 * LDA];
  __shared__ float bsh[256];

  int t = threadIdx.x, wave = t >> 6, lane = t & 63;
  int wrow = wave * 64;
  bsh[t] = bvec[l * 256 + t];

  f32x4 acc[4][8] = {};

  for (int kk = 0; kk < 256; kk += 32) {
#pragma unroll
    for (int it = 0; it < 4; ++it) {            // A: 256 rows x 32 k
      int slot = t + it * 256;
      int rr = slot >> 2, gg = slot & 3;
      *(uint4*)&As[rr * LDA + gg * 8] = *(const uint4*)&Tl[rr * 256 + kk + gg * 8];
    }
#pragma unroll
    for (int it = 0; it < 2; ++it) {            // B: transpose-stage 32k x 128px
      int slot = t + it * 256;
      int pg = slot & 15, kr = slot >> 4;
      uint4 v = *(const uint4*)&P[(size_t)(kk + kr) * MPAD + px0 + pg * 8];
      const unsigned short* vs = (const unsigned short*)&v;
      int krs = kr ^ ((pg & 3) << 3);           // k-block XOR swizzle (bank spread)
#pragma unroll
      for (int e = 0; e < 8; ++e) Bs[(pg * 8 + e) * LDA + krs] = vs[e];
    }
    __syncthreads();
    if (kk < wrow + 64) {                       // T is lower-triangular: skip dead k-tiles
      bf16x8 bfr[8];
#pragma unroll
      for (int fj = 0; fj < 8; ++fj) {
        int px = fj * 16 + (lane & 15);
        int gs = (lane >> 4) ^ ((px >> 3) & 3);
        bfr[fj] = *(const bf16x8*)&Bs[px * LDA + gs * 8];
      }
#pragma unroll
      for (int fi = 0; fi < 4; ++fi) {
        if (wrow + fi * 16 + 15 >= kk) {
          bf16x8 afr = *(const bf16x8*)&As[(wrow + fi * 16 + (lane & 15)) * LDA + (lane >> 4) * 8];
#pragma unroll
          for (int fj = 0; fj < 8; ++fj)
            acc[fi][fj] = __builtin_amdgcn_mfma_f32_16x16x32_bf16(afr, bfr[fj], acc[fi][fj], 0, 0, 0);
        }
      }
    }
    __syncthreads();
  }
#pragma unroll
  for (int fi = 0; fi < 4; ++fi)
#pragma unroll
    for (int fj = 0; fj < 8; ++fj) {
      long p = px0 + fj * 16 + (lane & 15);
#pragma unroll
      for (int rg = 0; rg < 4; ++rg) {
        int rr = wrow + fi * 16 + (lane >> 4) * 4 + rg;
        float v = acc[fi][fj][rg] + bsh[rr];
        P[(size_t)rr * MPAD + p] = f2bf(v);
      }
    }
}

// =============================================================================
extern "C" void kernel_launch(void* const* d_in, const int* in_sizes, int n_in,
                              void* d_out, int out_size, void* d_ws, size_t ws_size,
                              hipStream_t stream) {
  const float* cfeat = (const float*)d_in[0];
  const float* sfeat = (const float*)d_in[1];
  const int* seg_c   = (const int*)d_in[2];
  const int* seg_s   = (const int*)d_in[3];

  char* ws = (char*)d_ws;
  size_t o = 0;
  auto take = [&](size_t b) { size_t r = o; o += (b + 255) & ~(size_t)255; return r; };

  unsigned short* P  = (unsigned short*)(ws + take((size_t)NCH * MPAD * 2));
  size_t zero_b = o;
  float* G           = (float*)(ws + take((size_t)2 * 8 * 65536 * 4));
  float* Vinv        = (float*)(ws + take((size_t)8 * 65536 * 4));
  float* sum         = (float*)(ws + take((size_t)2 * 8 * 256 * 4));
  float* bacc        = (float*)(ws + take((size_t)8 * 256 * 4));
  int*   hist        = (int*)(ws + take((size_t)2 * 128 * 8 * 4));
  size_t zero_e = o;
  unsigned short* Tb = (unsigned short*)(ws + take((size_t)8 * 65536 * 2));
  float* Wg          = (float*)(ws + take((size_t)16 * 8 * 1024 * 4));
  int*   dst         = (int*)(ws + take((size_t)2 * M_PIX * 4));
  float* means       = (float*)(ws + take((size_t)2 * 8 * 256 * 4));
  float* bvec        = (float*)(ws + take((size_t)8 * 256 * 4));
  int*   base        = (int*)(ws + take((size_t)2 * 128 * 8 * 4));
  int*   off         = (int*)(ws + take((size_t)2 * 9 * 4));
  int*   cnt         = (int*)(ws + take((size_t)2 * 8 * 4));
  int*   valid       = (int*)(ws + take((size_t)8 * 4));
  (void)ws_size; (void)n_in; (void)in_sizes; (void)out_size;

  hipMemsetAsync(ws + zero_b, 0, zero_e - zero_b, stream);

  k_hist<<<dim3(128), dim3(256), 0, stream>>>(seg_c, seg_s, hist);
  k_scan<<<dim3(1), dim3(256), 0, stream>>>(hist, base, off, cnt, valid);
  k_rank<<<dim3(128), dim3(256), 0, stream>>>(seg_c, seg_s, base, dst);

  // style (side 1) first, then content (side 0); P is reused, stream-serial.
  for (int s = 1; s >= 0; --s) {
    const float* feat = s ? sfeat : cfeat;
    const int* seg = s ? seg_s : seg_c;
    k_padzero<<<dim3(9), dim3(256), 0, stream>>>(P, off + s * 9, cnt + s * 8);
    k_pack<<<dim3(128, 8), dim3(256), 0, stream>>>(feat, seg, dst + (size_t)s * M_PIX,
                                                   base + s * 1024, P);
    k_gram<<<dim3(260, 8), dim3(512), 0, stream>>>(P, off + s * 9, G + (size_t)s * 8 * 65536,
                                                   sum + (size_t)s * 8 * 256);
  }

  k_cov<<<dim3(16), dim3(256), 0, stream>>>(G, sum, cnt, means);
  for (int pb = 0; pb < 8; ++pb) {
    k_panel<<<dim3(16), dim3(256), 0, stream>>>(G, Wg, pb);
    if (pb < 7) k_trail<<<dim3(16, 10), dim3(256), 0, stream>>>(G, pb);
  }
  k_vinit<<<dim3(8), dim3(256), 0, stream>>>(Wg, Vinv);
  k_vlevel<32><<<dim3(32), dim3(512), 0, stream>>>(G, Vinv);
  k_vlevel<64><<<dim3(16), dim3(512), 0, stream>>>(G, Vinv);
  k_vlevel<128><<<dim3(8), dim3(512), 0, stream>>>(G, Vinv);
  k_tgemm<<<dim3(16, 8), dim3(256), 0, stream>>>(G, Vinv, means, valid, Tb, bacc);
  k_bvec<<<dim3(8), dim3(256), 0, stream>>>(means, bacc, valid, bvec);
  k_outgemm<<<dim3(2080), dim3(256), 0, stream>>>(P, Tb, bvec, off);
  k_unpack<<<dim3(128, 8), dim3(256), 0, stream>>>(P, seg_c, dst, base, (float*)d_out);
}